// Round 3
// baseline (104.616 us; speedup 1.0000x reference)
//
#include <hip/hip_runtime.h>

// ---------------------------------------------------------------------------
// LinearSelfAttention: out = Q@state + tril(Q Q^T,-1)@V ; new_state = state + Q^T V
// B=4 T=2048 nh=8 N=64 D=128.  R3: segment=64 (32 chunks), 3 dispatches:
//   phase1:  S_c[i][d] = sum_{t in chunk} Q[t][i] V[t][d]   (bf16 ws1, [i][d])
//   prefix:  P_c = state + sum_{c'<c} S_c'  (bf16 ws2, [i][d]); new_state fp32
//   phase2:  O_c = Q_c @ P_c + tril(Q_c Q_c^T,-1) @ V_c     (single chunk/block)
// MFMA = f32_16x16x32_bf16.  C/D: col=lane&15, row=quad*4+reg (m89-verified).
// A frag: A[m=lane&15][k=quad*8+j] (row-contiguous); B frag via B^T stored
// [n][k] so lane reads a contiguous row.
// R3 vs R2: chunk=64 everywhere (phase2 has no serial loop / no P update,
// 2 barriers, grid 1024), bf16 ws1, u32-pair prefix, id%8 XCD co-location.
// ---------------------------------------------------------------------------

using floatx4 = __attribute__((ext_vector_type(4))) float;
using float4v = __attribute__((ext_vector_type(4))) float;
using float2v = __attribute__((ext_vector_type(2))) float;
using shortx8 = __attribute__((ext_vector_type(8))) short;
using shortx4 = __attribute__((ext_vector_type(4))) short;
using uint2v  = __attribute__((ext_vector_type(2))) unsigned int;

#define MFMA16(a, b, c) __builtin_amdgcn_mfma_f32_16x16x32_bf16((a), (b), (c), 0, 0, 0)

__device__ __forceinline__ unsigned short f2bf(float f) {
  unsigned int u = __builtin_bit_cast(unsigned int, f);
  u += 0x7FFFu + ((u >> 16) & 1u);   // RNE
  return (unsigned short)(u >> 16);
}
__device__ __forceinline__ float bf2f(unsigned short h) {
  unsigned int u = ((unsigned int)h) << 16;
  return __builtin_bit_cast(float, u);
}
__device__ __forceinline__ unsigned int pack2(float a, float b) {
  return (unsigned int)f2bf(a) | ((unsigned int)f2bf(b) << 16);
}
__device__ __forceinline__ shortx8 lds8(const unsigned short* p) {
  shortx4 a = *(const shortx4*)p;
  shortx4 b = *(const shortx4*)(p + 4);
  return __builtin_shufflevector(a, b, 0, 1, 2, 3, 4, 5, 6, 7);
}

// Block-id decode shared by phase1/phase2: grid 1024.
// id = bcHigh*64 + n*8 + bcLow, bc = bcHigh*8 + bcLow, b = bc>>5, c = bc&31.
// The 8 blocks sharing (b,c) (i.e. sharing a V chunk) have ids differing by 8
// -> same id%8 -> same XCD under round-robin dispatch -> V shared in XCD L2.
#define DECODE_BNC()                                    \
  const int id = blockIdx.x;                            \
  const int n = (id >> 3) & 7;                          \
  const int bc = (id >> 6) * 8 + (id & 7);              \
  const int b = bc >> 5, c = bc & 31

// ---------------------------------------------------------------------------
// Phase 1: S_c[i][d] = sum_t Q[t][i] V[t][d].  grid 1024, block 256, K=64.
// Qt[i][t] ld=68, Vt[d][t] ld=68 (odd-u32 stride: 2-way max on paired writes,
// 2-way max on b64 fragment reads).  LDS 25.5 KB.
// ---------------------------------------------------------------------------
__global__ __launch_bounds__(256) void k_phase1(const float* __restrict__ Q,
                                                const float* __restrict__ V,
                                                unsigned short* __restrict__ ws1) {
  __shared__ unsigned short Qt[64 * 68];   // [i][t]
  __shared__ unsigned short Vt[128 * 68];  // [d][t]

  DECODE_BNC();
  const int tid = threadIdx.x;
  const float* qbase = Q + (((size_t)(b * 2048 + c * 64) * 8 + n) * 64);
  const float* vbase = V + ((size_t)(b * 2048 + c * 64) * 128);

  // convert-transpose staging: coalesced dword loads, paired-t u32 LDS writes
#pragma unroll
  for (int it = 0; it < 8; ++it) {          // Q: 64 i x 32 t-pairs
    int j = tid + it * 256;
    int i = j & 63, p = j >> 6;
    float q0 = qbase[(2 * p) * 512 + i];
    float q1 = qbase[(2 * p + 1) * 512 + i];
    *(unsigned int*)&Qt[i * 68 + 2 * p] = pack2(q0, q1);
  }
#pragma unroll
  for (int it = 0; it < 16; ++it) {         // V: 128 d x 32 t-pairs
    int j = tid + it * 256;
    int d = j & 127, p = j >> 7;
    float v0 = vbase[(2 * p) * 128 + d];
    float v1 = vbase[(2 * p + 1) * 128 + d];
    *(unsigned int*)&Vt[d * 68 + 2 * p] = pack2(v0, v1);
  }
  __syncthreads();

  const int wave = tid >> 6, lane = tid & 63;
  const int col = lane & 15, quad = lane >> 4;

  // D[m=i][n=d]: wave -> d-tiles {2w,2w+1}, all 4 i-tiles.  K=64 over t.
  floatx4 acc[4][2];
#pragma unroll
  for (int ti = 0; ti < 4; ++ti)
#pragma unroll
    for (int dj = 0; dj < 2; ++dj) acc[ti][dj] = (floatx4){0.f, 0.f, 0.f, 0.f};

#pragma unroll
  for (int s = 0; s < 2; ++s) {
    const int koff = s * 32 + quad * 8;
    shortx8 bv[2];
#pragma unroll
    for (int dj = 0; dj < 2; ++dj)
      bv[dj] = lds8(&Vt[((wave * 2 + dj) * 16 + col) * 68 + koff]);
#pragma unroll
    for (int ti = 0; ti < 4; ++ti) {
      shortx8 aq = lds8(&Qt[(ti * 16 + col) * 68 + koff]);
#pragma unroll
      for (int dj = 0; dj < 2; ++dj) acc[ti][dj] = MFMA16(aq, bv[dj], acc[ti][dj]);
    }
  }

  unsigned short* wbase = ws1 + (size_t)((b * 8 + n) * 32 + c) * 8192;
#pragma unroll
  for (int ti = 0; ti < 4; ++ti)
#pragma unroll
    for (int dj = 0; dj < 2; ++dj)
#pragma unroll
      for (int r = 0; r < 4; ++r) {
        int i = ti * 16 + quad * 4 + r;
        int d = (wave * 2 + dj) * 16 + col;
        wbase[i * 128 + d] = f2bf(acc[ti][dj][r]);
      }
}

// ---------------------------------------------------------------------------
// Prefix over 32 chunks, [i][d] layout, u32 bf16-pair processing.
// grid 512, block 256: thread -> (bn, d-pair).  All accesses coalesced.
// ---------------------------------------------------------------------------
__global__ __launch_bounds__(256) void k_prefix(const float* __restrict__ state,
                                                const unsigned int* __restrict__ ws1,
                                                unsigned int* __restrict__ ws2,
                                                float* __restrict__ new_state) {
  int t = blockIdx.x * 256 + threadIdx.x;   // 0 .. 131071
  int bn = t >> 12;
  int e2 = t & 4095;                         // u32 pair index within [i][d]
  float2v st = *(const float2v*)(state + (size_t)bn * 8192 + 2 * e2);
  float run0 = st.x, run1 = st.y;
  const unsigned int* w1 = ws1 + (size_t)bn * 32 * 4096 + e2;
  unsigned int* w2 = ws2 + (size_t)bn * 32 * 4096 + e2;
#pragma unroll
  for (int g = 0; g < 32; ++g) {
    w2[g * 4096] = pack2(run0, run1);
    unsigned int s = w1[g * 4096];
    run0 += bf2f((unsigned short)(s & 0xFFFFu));
    run1 += bf2f((unsigned short)(s >> 16));
  }
  float2v ns; ns.x = run0; ns.y = run1;
  *(float2v*)(new_state + (size_t)bn * 8192 + 2 * e2) = ns;
}

// ---------------------------------------------------------------------------
// Phase 2: one 64-chunk per block:  O = Q_c @ P_c + tril(Q_c Q_c^T,-1) @ V_c.
// grid 1024, block 256.  LDS 52 KB -> 3 blocks/CU.  Only 2 barriers.
// ---------------------------------------------------------------------------
__global__ __launch_bounds__(256) void k_phase2(const float* __restrict__ Q,
                                                const float* __restrict__ V,
                                                const unsigned short* __restrict__ ws2,
                                                float* __restrict__ out) {
  __shared__ unsigned short Qs[64 * 72];    // [t][k]  A-rows (b128) + B-rows for QQ^T
  __shared__ unsigned short Vt[128 * 68];   // [d][u]  B^T rows (b64 x2)
  __shared__ unsigned short Ss[64 * 72];    // [t][u]  masked scores, A-rows (b128)
  __shared__ unsigned short Pt[128 * 68];   // [d][i]  chunk-entry state, B^T rows

  DECODE_BNC();
  const int tid = threadIdx.x;
  const int wave = tid >> 6, lane = tid & 63;
  const int col = lane & 15, quad = lane >> 4;

  // stage Pt: ws2 [i][d] -> Pt[d][i]
  {
    const unsigned int* pb32 =
        (const unsigned int*)(ws2 + (size_t)((b * 8 + n) * 32 + c) * 8192);
#pragma unroll
    for (int it = 0; it < 16; ++it) {
      int j = tid + it * 256;
      int d2 = j & 63, i = j >> 6;
      unsigned int u = pb32[i * 64 + d2];   // coalesced: d2 fastest
      Pt[(2 * d2) * 68 + i] = (unsigned short)(u & 0xFFFFu);
      Pt[(2 * d2 + 1) * 68 + i] = (unsigned short)(u >> 16);
    }
  }

  const float* qbase = Q + (((size_t)(b * 2048 + c * 64) * 8 + n) * 64);
  const float* vbase = V + ((size_t)(b * 2048 + c * 64) * 128);
  float* obase = out + (((size_t)(b * 2048 + c * 64) * 8 + n) * 128);

  // ---- stage Qs [t][k] and Vt [d][u] ----
#pragma unroll
  for (int it = 0; it < 4; ++it) {
    int l = tid + it * 256;
    int t = l >> 4, k4 = (l & 15) * 4;
    float4v q = *(const float4v*)(qbase + (size_t)t * 512 + k4);
    uint2v u;
    u.x = pack2(q.x, q.y);
    u.y = pack2(q.z, q.w);
    *(uint2v*)&Qs[t * 72 + k4] = u;
  }
#pragma unroll
  for (int it = 0; it < 16; ++it) {
    int j = tid + it * 256;
    int d = j & 127, p = j >> 7;            // u = 2p, 2p+1
    float v0 = vbase[(size_t)(2 * p) * 128 + d];
    float v1 = vbase[(size_t)(2 * p + 1) * 128 + d];
    *(unsigned int*)&Vt[d * 68 + 2 * p] = pack2(v0, v1);
  }
  __syncthreads();   // B1: staging visible

  // ---- scores: S[t][u] = Q Q^T, strict-causal mask -> Ss ----
  {
    int job = 0;
    for (int ti = 0; ti < 4; ++ti)
      for (int ui = 0; ui <= (ti | 1); ++ui, ++job) {
        if ((job & 3) != wave) continue;
        if (ui > ti) {                      // masked tile read by K-loop: zero
#pragma unroll
          for (int r = 0; r < 4; ++r)
            Ss[(ti * 16 + quad * 4 + r) * 72 + ui * 16 + col] = 0;
        } else {
          floatx4 sc = (floatx4){0.f, 0.f, 0.f, 0.f};
#pragma unroll
          for (int s = 0; s < 2; ++s) {
            shortx8 at = *(const shortx8*)&Qs[(ti * 16 + col) * 72 + s * 32 + quad * 8];
            shortx8 au = *(const shortx8*)&Qs[(ui * 16 + col) * 72 + s * 32 + quad * 8];
            sc = MFMA16(at, au, sc);
          }
#pragma unroll
          for (int r = 0; r < 4; ++r) {
            int t = ti * 16 + quad * 4 + r, u = ui * 16 + col;
            Ss[t * 72 + u] = (u < t) ? f2bf(sc[r]) : (unsigned short)0;
          }
        }
      }
  }
  __syncthreads();   // B2: Ss visible

  // ---- O accum: wave -> d-tiles {2w,2w+1}, all 4 t-tiles ----
  floatx4 acc[4][2];
#pragma unroll
  for (int ti = 0; ti < 4; ++ti)
#pragma unroll
    for (int dj = 0; dj < 2; ++dj) acc[ti][dj] = (floatx4){0.f, 0.f, 0.f, 0.f};

  // Q @ P (K=64 over i)
#pragma unroll
  for (int s = 0; s < 2; ++s) {
    const int koff = s * 32 + quad * 8;
    shortx8 bp[2];
#pragma unroll
    for (int dj = 0; dj < 2; ++dj)
      bp[dj] = lds8(&Pt[((wave * 2 + dj) * 16 + col) * 68 + koff]);
#pragma unroll
    for (int ti = 0; ti < 4; ++ti) {
      shortx8 aq = *(const shortx8*)&Qs[(ti * 16 + col) * 72 + koff];
#pragma unroll
      for (int dj = 0; dj < 2; ++dj) acc[ti][dj] = MFMA16(aq, bp[dj], acc[ti][dj]);
    }
  }
  // S @ V (skip K-steps that are entirely above the diagonal)
#pragma unroll
  for (int s = 0; s < 2; ++s) {
    const int koff = s * 32 + quad * 8;
    shortx8 bv[2];
#pragma unroll
    for (int dj = 0; dj < 2; ++dj)
      bv[dj] = lds8(&Vt[((wave * 2 + dj) * 16 + col) * 68 + koff]);
    for (int ti = (s == 0 ? 0 : 2); ti < 4; ++ti) {
      shortx8 as = *(const shortx8*)&Ss[(ti * 16 + col) * 72 + koff];
#pragma unroll
      for (int dj = 0; dj < 2; ++dj) acc[ti][dj] = MFMA16(as, bv[dj], acc[ti][dj]);
    }
  }
  // store O chunk
#pragma unroll
  for (int ti = 0; ti < 4; ++ti)
#pragma unroll
    for (int dj = 0; dj < 2; ++dj)
#pragma unroll
      for (int r = 0; r < 4; ++r) {
        int t = ti * 16 + quad * 4 + r;
        int d = (wave * 2 + dj) * 16 + col;
        obase[(size_t)t * 1024 + d] = acc[ti][dj][r];
      }
}

// ---------------------------------------------------------------------------
extern "C" void kernel_launch(void* const* d_in, const int* in_sizes, int n_in,
                              void* d_out, int out_size, void* d_ws, size_t ws_size,
                              hipStream_t stream) {
  (void)in_sizes; (void)n_in; (void)out_size; (void)ws_size;
  const float* Q     = (const float*)d_in[0];
  const float* V     = (const float*)d_in[1];
  const float* state = (const float*)d_in[2];
  float* out        = (float*)d_out;
  float* new_state  = out + (size_t)4 * 2048 * 8 * 128;
  unsigned short* ws1 = (unsigned short*)d_ws;                       // 16.8 MB bf16 [bn][32][i][d]
  unsigned short* ws2 = ws1 + (size_t)32 * 32 * 8192;                // 16.8 MB bf16

  k_phase1<<<1024, 256, 0, stream>>>(Q, V, ws1);
  k_prefix<<<512, 256, 0, stream>>>(state, (const unsigned int*)ws1,
                                    (unsigned int*)ws2, new_state);
  k_phase2<<<1024, 256, 0, stream>>>(Q, V, ws2, out);
}